// Round 7
// baseline (10185.855 us; speedup 1.0000x reference)
//
#include <hip/hip_runtime.h>

typedef _Float16 v8h __attribute__((ext_vector_type(8)));
typedef float v4f __attribute__((ext_vector_type(4)));

#define NT 512
#define XSTR 344   // x row stride (halves): 688B, 16B-aligned
#define HSTR 1032  // h row stride (halves): 2064B, 16B-aligned

// ws layout (halves):
//  W1H [gp=ph*10+p, 0..79][512 tid][8]  at 0        (327680)
//  W1L                                  at 327680
//  W2H [s=p*2+ph2, 0..63][512 tid][8]   at 655360   (262144)
//  W2L                                  at 917504   (total 1179648 = 2.25 MB)
//  att (transposed actions, float)      at byte 2359296
static constexpr size_t ATT_BYTES_NEEDED = 2359296ull + 4096ull * 64 * 64 * 4;

#define MFMA16 __builtin_amdgcn_mfma_f32_16x16x32_f16

__device__ __forceinline__ float tanh_fast(float a) {
  float e = __expf(2.0f * a);          // inf for large a -> +/-1 exactly
  return 1.0f - __fdividef(2.0f, e + 1.0f);
}

extern "C" __global__ void conv_w(const float* __restrict__ W1,
                                  const float* __restrict__ W2,
                                  _Float16* __restrict__ ws) {
  int i = blockIdx.x * 256 + threadIdx.x;        // 917504 total
  if (i < 327680) {
    int j = i & 7, lane = (i >> 3) & 63, w = (i >> 9) & 7, gp = i >> 12;
    int g = lane >> 4, l15 = lane & 15;
    int ph = gp / 10, p = gp % 10;
    float v = W1[(p * 32 + g * 8 + j) * 1024 + ph * 128 + w * 16 + l15];
    _Float16 hh = (_Float16)v;
    ws[i] = hh;
    ws[327680 + i] = (_Float16)((v - (float)hh) * 2048.f);
  } else {
    int iq = i - 655360;
    if (iq >= 0 && iq < 262144) {
      int j = iq & 7, t = (iq >> 3) & 511, s = iq >> 12;
      int lane = t & 63, wave = t >> 6, g = lane >> 4, l15 = lane & 15;
      int p = s >> 1, ph2 = s & 1;
      float v = W2[(p * 32 + g * 8 + j) * 256 + ph2 * 128 + wave * 16 + l15];
      _Float16 hh = (_Float16)v;
      ws[655360 + iq] = hh;
      ws[917504 + iq] = (_Float16)((v - (float)hh) * 2048.f);
    }
  }
}

extern "C" __global__ void conv_a(const float* __restrict__ actions,
                                  float* __restrict__ att) {
  size_t o = (size_t)blockIdx.x * 256 + threadIdx.x;   // 16777216 total
  int f = (int)(o & 63);
  int b = (int)((o >> 6) & 4095);
  int t = (int)(o >> 18);
  att[o] = actions[((size_t)b * 64 + f) * 64 + t];
}

extern "C" __global__ void __launch_bounds__(NT, 2)
ode_kernel(const float* __restrict__ actions, const float* __restrict__ att,
           const float* __restrict__ y0,
           const float* __restrict__ b1f, const float* __restrict__ b2f,
           const float* __restrict__ dtp, const _Float16* __restrict__ ws,
           float* __restrict__ out)
{
  __shared__ __align__(16) _Float16 xHs[16 * XSTR], xLs[16 * XSTR];
  __shared__ __align__(16) _Float16 hHs[16 * HSTR], hLs[16 * HSTR];
  __shared__ float b1s[1024];

  const int tid  = threadIdx.x;
  const int lane = tid & 63;
  const int l15  = lane & 15, g = lane >> 4;
  const int nloc = (tid >> 6) * 16 + l15;
  const int b0   = blockIdx.x * 16;
  const float dt = dtp[0];

  const size_t tid8 = (size_t)tid * 8;
  const _Float16* w1h = ws + tid8;              // + gp*4096
  const _Float16* w1l = ws + 327680 + tid8;
  const _Float16* w2h = ws + 655360 + tid8;     // + s*4096
  const _Float16* w2l = ws + 917504 + tid8;

  for (int i = tid; i < 1024; i += NT) b1s[i] = b1f[i];
  const float b2r0 = b2f[nloc], b2r1 = b2f[128 + nloc];

  // y state in registers
  float ya[4], yb[4];
  #pragma unroll
  for (int j = 0; j < 4; ++j) {
    int m = g * 4 + j;
    ya[j] = y0[(size_t)(b0 + m) * 256 + nloc];
    yb[j] = y0[(size_t)(b0 + m) * 256 + 128 + nloc];
    out[((size_t)((b0 + m) * 256 + nloc)) * 64] = ya[j];
    out[((size_t)((b0 + m) * 256 + 128 + nloc)) * 64] = yb[j];
  }

  const int xbase = l15 * XSTR + g * 8;
  const int hbase = l15 * HSTR + g * 8;

  v8h B1h[10], B1l[10];      // B1 ring: depth 10 (one ph period)
  v8h B2h[2][4], B2l[2][4];  // B2 ring: depth 4 per n-phase
  v8h Xh[5], Xl[5];          // x-frag ring: depth 5, 5-body lookahead
  v8h Hh[4], Hl[4];          // h-frag ring: depth 4, 4-body lookahead

  // prologue: B1 ph=0 sites for t=0
  #pragma unroll
  for (int p = 0; p < 10; ++p) {
    B1h[p] = *(const v8h*)(w1h + p * 4096);
    B1l[p] = *(const v8h*)(w1l + p * 4096);
  }

  #pragma unroll 1
  for (int t = 0; t < 63; ++t) {
    // ---- x-phase: x = [a_t | y] hi/lo planes
    #pragma unroll
    for (int it = 0; it < 2; ++it) {
      int o = tid + NT * it;
      int m = o >> 6, k = o & 63;
      float v = att ? att[((size_t)t * 4096 + b0 + m) * 64 + k]
                    : actions[((size_t)(b0 + m) * 64 + k) * 64 + t];
      _Float16 hh = (_Float16)v;
      xHs[m * XSTR + k] = hh;
      xLs[m * XSTR + k] = (_Float16)((v - (float)hh) * 2048.f);
    }
    #pragma unroll
    for (int j = 0; j < 4; ++j) {
      int m = g * 4 + j;
      _Float16 h0 = (_Float16)ya[j];
      xHs[m * XSTR + 64 + nloc] = h0;
      xLs[m * XSTR + 64 + nloc] = (_Float16)((ya[j] - (float)h0) * 2048.f);
      _Float16 h1 = (_Float16)yb[j];
      xHs[m * XSTR + 192 + nloc] = h1;
      xLs[m * XSTR + 192 + nloc] = (_Float16)((yb[j] - (float)h1) * 2048.f);
    }
    __syncthreads();   // x visible; B1 ph=0 loads drained

    // preload x-frag ring slots 0..4
    #pragma unroll
    for (int s = 0; s < 5; ++s) {
      Xh[s] = *(const v8h*)&xHs[xbase + s * 32];
      Xl[s] = *(const v8h*)&xLs[xbase + s * 32];
    }

    // ======== GEMM1: ph real-outer, p static-inner; rings B1(10), X(5) ====
    const _Float16* w1hp = w1h;
    const _Float16* w1lp = w1l;
    #pragma unroll 1
    for (int ph = 0; ph < 8; ++ph) {
      const float bb = b1s[ph * 128 + nloc];
      v4f accH = v4f{bb, bb, bb, bb};
      v4f accM = v4f{0.f, 0.f, 0.f, 0.f};
      #pragma unroll
      for (int p = 0; p < 10; ++p) {
        const int xs = p % 5;                    // static slot
        v8h xch = Xh[xs], xcl = Xl[xs];
        v8h bh = B1h[p], bl = B1l[p];
        if (ph < 7) {   // reload B1 slot for ph+1 (consumed 10 bodies later)
          B1h[p] = *(const v8h*)(w1hp + 40960 + p * 4096);
          B1l[p] = *(const v8h*)(w1lp + 40960 + p * 4096);
        } else if (p < 8) {   // ph==7: GEMM2 prologue, sites s=p
          B2h[p & 1][p >> 1] = *(const v8h*)(w2h + p * 4096);
          B2l[p & 1][p >> 1] = *(const v8h*)(w2l + p * 4096);
        }
        // reload x slot with frag (p+5)%10 (consumed 5 bodies later)
        if (p < 5) {
          Xh[xs] = *(const v8h*)&xHs[xbase + (p + 5) * 32];
          Xl[xs] = *(const v8h*)&xLs[xbase + (p + 5) * 32];
        } else if (ph < 7) {
          Xh[xs] = *(const v8h*)&xHs[xbase + (p - 5) * 32];
          Xl[xs] = *(const v8h*)&xLs[xbase + (p - 5) * 32];
        }
        accH = MFMA16(xch, bh, accH, 0, 0, 0);
        accM = MFMA16(xch, bl, accM, 0, 0, 0);
        accM = MFMA16(xcl, bh, accM, 0, 0, 0);
      }
      // epilogue: tanh + hi/lo split -> h planes
      #pragma unroll
      for (int j = 0; j < 4; ++j) {
        float v = accH[j] + accM[j] * (1.f / 2048.f);
        float th = tanh_fast(v);
        _Float16 hh = (_Float16)th;
        int m = g * 4 + j;
        hHs[m * HSTR + ph * 128 + nloc] = hh;
        hLs[m * HSTR + ph * 128 + nloc] = (_Float16)((th - (float)hh) * 2048.f);
      }
      w1hp += 40960; w1lp += 40960;
    }
    __syncthreads();   // h visible; B2 sites 0..7 drained

    // preload h-frag ring slots 0..3
    #pragma unroll
    for (int s = 0; s < 4; ++s) {
      Hh[s] = *(const v8h*)&hHs[hbase + s * 32];
      Hl[s] = *(const v8h*)&hLs[hbase + s * 32];
    }

    // ======== GEMM2: po real-outer (8), u static-inner (4); rings B2,H(4) ==
    v4f c0H = v4f{b2r0, b2r0, b2r0, b2r0}, c0M = v4f{0.f, 0.f, 0.f, 0.f};
    v4f c1H = v4f{b2r1, b2r1, b2r1, b2r1}, c1M = v4f{0.f, 0.f, 0.f, 0.f};
    #pragma unroll 1
    for (int po = 0; po < 8; ++po) {
      #pragma unroll
      for (int u = 0; u < 4; ++u) {
        const int p = po * 4 + u;
        v8h hh0 = Hh[u], hl0 = Hl[u];
        v8h bh0 = B2h[0][u], bl0 = B2l[0][u];
        v8h bh1 = B2h[1][u], bl1 = B2l[1][u];
        if (po < 7) {   // reload B2 slots for p+4 (sites 2(p+4), 2(p+4)+1)
          B2h[0][u] = *(const v8h*)(w2h + (size_t)(2 * (p + 4)) * 4096);
          B2l[0][u] = *(const v8h*)(w2l + (size_t)(2 * (p + 4)) * 4096);
          B2h[1][u] = *(const v8h*)(w2h + (size_t)(2 * (p + 4) + 1) * 4096);
          B2l[1][u] = *(const v8h*)(w2l + (size_t)(2 * (p + 4) + 1) * 4096);
          // reload h slot with frag p+4 (consumed 4 bodies later)
          Hh[u] = *(const v8h*)&hHs[hbase + (p + 4) * 32];
          Hl[u] = *(const v8h*)&hLs[hbase + (p + 4) * 32];
        }
        c0H = MFMA16(hh0, bh0, c0H, 0, 0, 0);
        c0M = MFMA16(hh0, bl0, c0M, 0, 0, 0);
        c0M = MFMA16(hl0, bh0, c0M, 0, 0, 0);
        c1H = MFMA16(hh0, bh1, c1H, 0, 0, 0);
        c1M = MFMA16(hh0, bl1, c1M, 0, 0, 0);
        c1M = MFMA16(hl0, bh1, c1M, 0, 0, 0);
      }
    }
    // y epilogue + out stores
    #pragma unroll
    for (int j = 0; j < 4; ++j) {
      int m = g * 4 + j;
      float yn0 = ya[j] + dt * (c0H[j] + c0M[j] * (1.f / 2048.f));
      ya[j] = yn0;
      out[((size_t)((b0 + m) * 256 + nloc)) * 64 + (t + 1)] = yn0;
      float yn1 = yb[j] + dt * (c1H[j] + c1M[j] * (1.f / 2048.f));
      yb[j] = yn1;
      out[((size_t)((b0 + m) * 256 + 128 + nloc)) * 64 + (t + 1)] = yn1;
    }
    // prefetch next step's B1 ph=0 sites (drained by next x-barrier)
    if (t < 62) {
      #pragma unroll
      for (int p = 0; p < 10; ++p) {
        B1h[p] = *(const v8h*)(w1h + p * 4096);
        B1l[p] = *(const v8h*)(w1l + p * 4096);
      }
    }
  }
}

extern "C" void kernel_launch(void* const* d_in, const int* in_sizes, int n_in,
                              void* d_out, int out_size, void* d_ws, size_t ws_size,
                              hipStream_t stream) {
  const float* actions = (const float*)d_in[1];
  const float* y0      = (const float*)d_in[2];
  const float* W1      = (const float*)d_in[3];
  const float* b1      = (const float*)d_in[4];
  const float* W2      = (const float*)d_in[5];
  const float* b2      = (const float*)d_in[6];
  const float* dtp     = (const float*)d_in[7];
  float* out = (float*)d_out;
  _Float16* ws = (_Float16*)d_ws;

  const bool use_att = ws_size >= ATT_BYTES_NEEDED;
  float* att = use_att ? (float*)((char*)d_ws + 2359296) : nullptr;

  hipLaunchKernelGGL(conv_w, dim3(3584), dim3(256), 0, stream, W1, W2, ws);
  if (use_att)
    hipLaunchKernelGGL(conv_a, dim3(65536), dim3(256), 0, stream, actions, att);
  hipLaunchKernelGGL(ode_kernel, dim3(256), dim3(NT), 0, stream,
                     actions, att, y0, b1, b2, dtp, ws, out);
}

// Round 8
// 2334.643 us; speedup vs baseline: 4.3629x; 4.3629x over previous
//
#include <hip/hip_runtime.h>

typedef _Float16 v8h __attribute__((ext_vector_type(8)));
typedef float v4f __attribute__((ext_vector_type(4)));

#define NT 512
#define XSTR 344   // x row stride (halves)
#define HSTR 1032  // h row stride (halves)

// ws layout (halves):
//  W1H [site gp=ph*10+p, 0..79][512 tid][8]  at 0        (327680)
//  W1L                                       at 327680
//  W2H [site s=p*2+ph2, 0..63][512 tid][8]   at 655360   (262144)
//  W2L                                       at 917504   (total 1179648 = 2.25 MB)
//  att (transposed actions, float)           at byte 2359296
static constexpr size_t ATT_BYTES_NEEDED = 2359296ull + 4096ull * 64 * 64 * 4;

#define MFMA16 __builtin_amdgcn_mfma_f32_16x16x32_f16

// pinned async load: compiler cannot sink/spill; completion via hand vmcnt
#define GLOAD(dst, base, vo) \
  asm volatile("global_load_dwordx4 %0, %1, %2" : "=v"(dst) : "v"(vo), "s"(base))
#define VMW_(n) asm volatile("s_waitcnt vmcnt(" #n ")" ::: "memory")
#define VMW(n) do { VMW_(n); __builtin_amdgcn_sched_barrier(0); } while (0)
#define LGKMBAR() do { asm volatile("s_waitcnt lgkmcnt(0)" ::: "memory"); \
  __builtin_amdgcn_s_barrier(); } while (0)

__device__ __forceinline__ float tanh_fast(float a) {
  float e = __expf(2.0f * a);
  return 1.0f - __fdividef(2.0f, e + 1.0f);
}

extern "C" __global__ void conv_w(const float* __restrict__ W1,
                                  const float* __restrict__ W2,
                                  _Float16* __restrict__ ws) {
  int i = blockIdx.x * 256 + threadIdx.x;        // 917504 total
  if (i < 327680) {
    int j = i & 7, lane = (i >> 3) & 63, w = (i >> 9) & 7, gp = i >> 12;
    int g = lane >> 4, l15 = lane & 15;
    int ph = gp / 10, p = gp % 10;
    float v = W1[(p * 32 + g * 8 + j) * 1024 + ph * 128 + w * 16 + l15];
    _Float16 hh = (_Float16)v;
    ws[i] = hh;
    ws[327680 + i] = (_Float16)((v - (float)hh) * 2048.f);
  } else {
    int iq = i - 655360;
    if (iq >= 0) {
      int j = iq & 7, t = (iq >> 3) & 511, s = iq >> 12;
      int lane = t & 63, wave = t >> 6, g = lane >> 4, l15 = lane & 15;
      int p = s >> 1, ph2 = s & 1;
      float v = W2[(p * 32 + g * 8 + j) * 256 + ph2 * 128 + wave * 16 + l15];
      _Float16 hh = (_Float16)v;
      ws[655360 + iq] = hh;
      ws[917504 + iq] = (_Float16)((v - (float)hh) * 2048.f);
    }
  }
}

extern "C" __global__ void conv_a(const float* __restrict__ actions,
                                  float* __restrict__ att) {
  size_t o = (size_t)blockIdx.x * 256 + threadIdx.x;
  int f = (int)(o & 63);
  int b = (int)((o >> 6) & 4095);
  int t = (int)(o >> 18);
  att[o] = actions[((size_t)b * 64 + f) * 64 + t];
}

// G1 body p (0..9): wait N, consume ring slot p%5, refill site+5 if RF,
// rotate x frag (reads frag 0 for next ph when p==9 && RD0)
#define G1BODY(p, RF, N, RD0) do { \
    VMW(N); \
    v8h bh = B1H[(p) % 5], bl = B1L[(p) % 5]; \
    if (RF) { GLOAD(B1H[(p) % 5], w1hB, vo1); GLOAD(B1L[(p) % 5], w1lB, vo1); \
              vo1 += 8192; } \
    v8h xch = Xh[(p) & 1], xcl = Xl[(p) & 1]; \
    if ((p) < 9) { \
      Xh[((p) + 1) & 1] = *(const v8h*)&xHs[xbase + ((p) + 1) * 32]; \
      Xl[((p) + 1) & 1] = *(const v8h*)&xLs[xbase + ((p) + 1) * 32]; \
    } else if (RD0) { \
      Xh[0] = *(const v8h*)&xHs[xbase]; \
      Xl[0] = *(const v8h*)&xLs[xbase]; \
    } \
    accH = MFMA16(xch, bh, accH, 0, 0, 0); \
    accM = MFMA16(xch, bl, accM, 0, 0, 0); \
    accM = MFMA16(xcl, bh, accM, 0, 0, 0); \
  } while (0)

// G2 body j: slot s3 (=j%3, passed literal), parity par (=j&1), refill j+3 if RF
#define G2BODY(j, s3, par, RF, N) do { \
    VMW(N); \
    v8h bh0 = B2H0[s3], bl0 = B2L0[s3]; \
    v8h bh1 = B2H1[s3], bl1 = B2L1[s3]; \
    if (RF) { \
      GLOAD(B2H0[s3], w2hB, vo2); GLOAD(B2L0[s3], w2lB, vo2); \
      GLOAD(B2H1[s3], w2hB, vo2 + 8192); GLOAD(B2L1[s3], w2lB, vo2 + 8192); \
      vo2 += 16384; \
    } \
    v8h hch = Hh[par], hcl = Hl_[par]; \
    if ((j) < 31) { \
      Hh[(par) ^ 1] = *(const v8h*)&hHs[hbase + ((j) + 1) * 32]; \
      Hl_[(par) ^ 1] = *(const v8h*)&hLs[hbase + ((j) + 1) * 32]; \
    } \
    c0H = MFMA16(hch, bh0, c0H, 0, 0, 0); \
    c0M = MFMA16(hch, bl0, c0M, 0, 0, 0); \
    c0M = MFMA16(hcl, bh0, c0M, 0, 0, 0); \
    c1H = MFMA16(hch, bh1, c1H, 0, 0, 0); \
    c1M = MFMA16(hch, bl1, c1M, 0, 0, 0); \
    c1M = MFMA16(hcl, bh1, c1M, 0, 0, 0); \
  } while (0)

extern "C" __global__ void __launch_bounds__(NT, 2)
ode_kernel(const float* __restrict__ actions, const float* __restrict__ att,
           const float* __restrict__ y0,
           const float* __restrict__ b1f, const float* __restrict__ b2f,
           const float* __restrict__ dtp, const _Float16* __restrict__ ws,
           float* __restrict__ out)
{
  __shared__ __align__(16) _Float16 xHs[16 * XSTR], xLs[16 * XSTR];
  __shared__ __align__(16) _Float16 hHs[16 * HSTR], hLs[16 * HSTR];
  __shared__ float b1s[1024];

  const int tid  = threadIdx.x;
  const int lane = tid & 63;
  const int l15  = lane & 15, g = lane >> 4;
  const int nloc = (tid >> 6) * 16 + l15;
  const int b0   = blockIdx.x * 16;
  const float dt = dtp[0];
  const int tid16 = tid * 16;   // byte offset of this thread's 16B frag

  const _Float16* w1hB = ws;
  const _Float16* w1lB = ws + 327680;
  const _Float16* w2hB = ws + 655360;
  const _Float16* w2lB = ws + 917504;

  for (int i = tid; i < 1024; i += NT) b1s[i] = b1f[i];
  const float b2r0 = b2f[nloc], b2r1 = b2f[128 + nloc];

  float ya[4], yb[4];
  #pragma unroll
  for (int j = 0; j < 4; ++j) {
    int m = g * 4 + j;
    ya[j] = y0[(size_t)(b0 + m) * 256 + nloc];
    yb[j] = y0[(size_t)(b0 + m) * 256 + 128 + nloc];
    out[((size_t)((b0 + m) * 256 + nloc)) * 64] = ya[j];
    out[((size_t)((b0 + m) * 256 + 128 + nloc)) * 64] = yb[j];
  }

  const int xbase = l15 * XSTR + g * 8;
  const int hbase = l15 * HSTR + g * 8;

  v8h B1H[5], B1L[5];              // G1 ring: depth 5 (5 | 10, slots static)
  v8h B2H0[3], B2L0[3], B2H1[3], B2L1[3];   // G2 ring: depth 3 bodies
  v8h Xh[2], Xl[2], Hh[2], Hl_[2];

  // initial G1 prologue: sites 0..4
  #pragma unroll
  for (int s = 0; s < 5; ++s) {
    GLOAD(B1H[s], w1hB, tid16 + s * 8192);
    GLOAD(B1L[s], w1lB, tid16 + s * 8192);
  }

  #pragma unroll 1
  for (int t = 0; t < 63; ++t) {
    // ---- x-phase: x = [a_t | y] hi/lo planes
    #pragma unroll
    for (int it = 0; it < 2; ++it) {
      int o = tid + NT * it;
      int m = o >> 6, k = o & 63;
      float v = att ? att[((size_t)t * 4096 + b0 + m) * 64 + k]
                    : actions[((size_t)(b0 + m) * 64 + k) * 64 + t];
      _Float16 hh = (_Float16)v;
      xHs[m * XSTR + k] = hh;
      xLs[m * XSTR + k] = (_Float16)((v - (float)hh) * 2048.f);
    }
    #pragma unroll
    for (int j = 0; j < 4; ++j) {
      int m = g * 4 + j;
      _Float16 h0 = (_Float16)ya[j];
      xHs[m * XSTR + 64 + nloc] = h0;
      xLs[m * XSTR + 64 + nloc] = (_Float16)((ya[j] - (float)h0) * 2048.f);
      _Float16 h1 = (_Float16)yb[j];
      xHs[m * XSTR + 192 + nloc] = h1;
      xLs[m * XSTR + 192 + nloc] = (_Float16)((yb[j] - (float)h1) * 2048.f);
    }
    LGKMBAR();   // x visible; weight loads stay in flight (no vmcnt drain)

    // preload x frag 0
    Xh[0] = *(const v8h*)&xHs[xbase];
    Xl[0] = *(const v8h*)&xLs[xbase];

    int vo1 = tid16 + 5 * 8192;   // next G1 refill site = 5

    // ======== GEMM1 ph 0..6: uniform bodies, vmcnt(8), refill +5 ========
    #pragma unroll 1
    for (int ph = 0; ph < 7; ++ph) {
      const float bb = b1s[ph * 128 + nloc];
      v4f accH = v4f{bb, bb, bb, bb};
      v4f accM = v4f{0.f, 0.f, 0.f, 0.f};
      #pragma unroll
      for (int p = 0; p < 10; ++p) G1BODY(p, 1, 8, 1);
      #pragma unroll
      for (int j = 0; j < 4; ++j) {
        float v = accH[j] + accM[j] * (1.f / 2048.f);
        float th = tanh_fast(v);
        _Float16 hh = (_Float16)th;
        int m = g * 4 + j;
        hHs[m * HSTR + ph * 128 + nloc] = hh;
        hLs[m * HSTR + ph * 128 + nloc] = (_Float16)((th - (float)hh) * 2048.f);
      }
    }
    // ======== GEMM1 ph 7 (tail): refills end at site 79; G2 prologue ========
    {
      const float bb = b1s[7 * 128 + nloc];
      v4f accH = v4f{bb, bb, bb, bb};
      v4f accM = v4f{0.f, 0.f, 0.f, 0.f};
      #pragma unroll
      for (int p = 0; p < 6; ++p) G1BODY(p, (p) < 5, 8, 1);
      G1BODY(6, 0, 6, 1);
      GLOAD(B2H0[0], w2hB, tid16);          GLOAD(B2L0[0], w2lB, tid16);
      GLOAD(B2H1[0], w2hB, tid16 + 8192);   GLOAD(B2L1[0], w2lB, tid16 + 8192);
      G1BODY(7, 0, 8, 1);
      GLOAD(B2H0[1], w2hB, tid16 + 16384);  GLOAD(B2L0[1], w2lB, tid16 + 16384);
      GLOAD(B2H1[1], w2hB, tid16 + 24576);  GLOAD(B2L1[1], w2lB, tid16 + 24576);
      G1BODY(8, 0, 10, 1);
      GLOAD(B2H0[2], w2hB, tid16 + 32768);  GLOAD(B2L0[2], w2lB, tid16 + 32768);
      GLOAD(B2H1[2], w2hB, tid16 + 40960);  GLOAD(B2L1[2], w2lB, tid16 + 40960);
      G1BODY(9, 0, 12, 0);
      #pragma unroll
      for (int j = 0; j < 4; ++j) {
        float v = accH[j] + accM[j] * (1.f / 2048.f);
        float th = tanh_fast(v);
        _Float16 hh = (_Float16)th;
        int m = g * 4 + j;
        hHs[m * HSTR + 7 * 128 + nloc] = hh;
        hLs[m * HSTR + 7 * 128 + nloc] = (_Float16)((th - (float)hh) * 2048.f);
      }
    }
    LGKMBAR();   // h visible; G2 slots 0..2 loads stay in flight

    // preload h frag 0
    Hh[0] = *(const v8h*)&hHs[hbase];
    Hl_[0] = *(const v8h*)&hLs[hbase];

    int vo2 = tid16 + 3 * 16384;   // next G2 refill = body 3's sites

    v4f c0H = v4f{b2r0, b2r0, b2r0, b2r0}, c0M = v4f{0.f, 0.f, 0.f, 0.f};
    v4f c1H = v4f{b2r1, b2r1, b2r1, b2r1}, c1M = v4f{0.f, 0.f, 0.f, 0.f};

    // ======== GEMM2: bodies 0..23 uniform (6-body groups), tail peeled ======
    #pragma unroll 1
    for (int jj = 0; jj < 4; ++jj) {
      const int jb = jj * 6;
      G2BODY(jb + 0, 0, 0, 1, 8);
      G2BODY(jb + 1, 1, 1, 1, 8);
      G2BODY(jb + 2, 2, 0, 1, 8);
      G2BODY(jb + 3, 0, 1, 1, 8);
      G2BODY(jb + 4, 1, 0, 1, 8);
      G2BODY(jb + 5, 2, 1, 1, 8);
    }
    G2BODY(24, 0, 0, 1, 8);
    G2BODY(25, 1, 1, 1, 8);
    G2BODY(26, 2, 0, 1, 8);
    G2BODY(27, 0, 1, 1, 8);
    G2BODY(28, 1, 0, 1, 8);
    G2BODY(29, 2, 1, 0, 8);
    G2BODY(30, 0, 0, 0, 4);
    G2BODY(31, 1, 1, 0, 0);

    // ---- y epilogue + out stores
    #pragma unroll
    for (int j = 0; j < 4; ++j) {
      int m = g * 4 + j;
      float yn0 = ya[j] + dt * (c0H[j] + c0M[j] * (1.f / 2048.f));
      ya[j] = yn0;
      out[((size_t)((b0 + m) * 256 + nloc)) * 64 + (t + 1)] = yn0;
      float yn1 = yb[j] + dt * (c1H[j] + c1M[j] * (1.f / 2048.f));
      yb[j] = yn1;
      out[((size_t)((b0 + m) * 256 + 128 + nloc)) * 64 + (t + 1)] = yn1;
    }
    // ---- next step's G1 prologue (sites 0..4); lands during x-phase+barrier
    if (t < 62) {
      #pragma unroll
      for (int s = 0; s < 5; ++s) {
        GLOAD(B1H[s], w1hB, tid16 + s * 8192);
        GLOAD(B1L[s], w1lB, tid16 + s * 8192);
      }
    }
  }
}

extern "C" void kernel_launch(void* const* d_in, const int* in_sizes, int n_in,
                              void* d_out, int out_size, void* d_ws, size_t ws_size,
                              hipStream_t stream) {
  const float* actions = (const float*)d_in[1];
  const float* y0      = (const float*)d_in[2];
  const float* W1      = (const float*)d_in[3];
  const float* b1      = (const float*)d_in[4];
  const float* W2      = (const float*)d_in[5];
  const float* b2      = (const float*)d_in[6];
  const float* dtp     = (const float*)d_in[7];
  float* out = (float*)d_out;
  _Float16* ws = (_Float16*)d_ws;

  const bool use_att = ws_size >= ATT_BYTES_NEEDED;
  float* att = use_att ? (float*)((char*)d_ws + 2359296) : nullptr;

  hipLaunchKernelGGL(conv_w, dim3(3584), dim3(256), 0, stream, W1, W2, ws);
  if (use_att)
    hipLaunchKernelGGL(conv_a, dim3(65536), dim3(256), 0, stream, actions, att);
  hipLaunchKernelGGL(ode_kernel, dim3(256), dim3(NT), 0, stream,
                     actions, att, y0, b1, b2, dtp, ws, out);
}